// Round 6
// baseline (34013.364 us; speedup 1.0000x reference)
//
#include <hip/hip_runtime.h>

#define SENC 1025
#define SPENC 1032
#define NBE 129
#define SDEC 1024
#define NBD 128
#define BATCH 32
#define MENC (BATCH * SPENC)  /* 33024 */
#define MDEC (BATCH * SDEC)   /* 32768 */

// ---------- beacon: signals unrecognized input ordering ----------
__global__ void beacon_k(float* out) { if (threadIdx.x == 0) out[0] = 1000.0f; }

// ---------- embed ----------
__global__ __launch_bounds__(256) void embed_k(const float* __restrict__ x, const float* __restrict__ Wd,
    const float* __restrict__ bd, const float* __restrict__ emb, float* __restrict__ h)
{
  size_t gid = (size_t)blockIdx.x * 256 + threadIdx.x;  // MENC*512
  int dd = (int)(gid & 511);
  size_t rs = gid >> 9;
  int s = (int)(rs % SPENC);
  int b = (int)(rs / SPENC);
  float v;
  if (s == 0) {
    v = emb[dd];
  } else if (s < SENC) {
    float acc = bd[dd];
    const float* xr = x + ((size_t)b * 1024 + (s - 1)) * 16;
    #pragma unroll
    for (int j = 0; j < 16; ++j) acc += xr[j] * Wd[j * 512 + dd];
    v = acc + emb[(size_t)s * 512 + dd];
  } else {
    v = 0.f;
  }
  h[gid] = v;
}

// ---------- tiled fp32 GEMM ----------
__device__ __forceinline__ void ld4f(const float* p, float* o) {
  float4 v = *(const float4*)p; o[0]=v.x; o[1]=v.y; o[2]=v.z; o[3]=v.w;
}

template<bool RELU, bool RESID>
__global__ __launch_bounds__(256) void gemm_k(const float* __restrict__ A, const float* __restrict__ W,
    const float* __restrict__ bias, const float* R, float* C, int M, int N, int K)
{
  __shared__ float As[16][64];
  __shared__ float Bs[16][64];
  int t = threadIdx.x;
  int n0 = blockIdx.x * 64, m0 = blockIdx.y * 64;
  int tx = t & 15, ty = t >> 4;
  int arow = t >> 2, akq = (t & 3) << 2;
  int brow = t >> 4, bnq = (t & 15) << 2;
  const float* Ap = A + (size_t)(m0 + arow) * K + akq;
  const float* Wp = W + (size_t)brow * N + n0 + bnq;
  float acc[4][4];
  #pragma unroll
  for (int i = 0; i < 4; ++i)
    #pragma unroll
    for (int j = 0; j < 4; ++j) acc[i][j] = 0.f;

  for (int k0 = 0; k0 < K; k0 += 16) {
    float avv[4], bvv[4];
    ld4f(Ap + k0, avv);
    ld4f(Wp + (size_t)k0 * N, bvv);
    __syncthreads();
    #pragma unroll
    for (int j = 0; j < 4; ++j) { As[akq + j][arow] = avv[j]; Bs[brow][bnq + j] = bvv[j]; }
    __syncthreads();
    #pragma unroll
    for (int k = 0; k < 16; ++k) {
      float aa[4], bb[4];
      #pragma unroll
      for (int i = 0; i < 4; ++i) aa[i] = As[k][ty * 4 + i];
      #pragma unroll
      for (int j = 0; j < 4; ++j) bb[j] = Bs[k][tx * 4 + j];
      #pragma unroll
      for (int i = 0; i < 4; ++i)
        #pragma unroll
        for (int j = 0; j < 4; ++j) acc[i][j] += aa[i] * bb[j];
    }
  }

  #pragma unroll
  for (int i = 0; i < 4; ++i) {
    int m = m0 + ty * 4 + i;
    int nbase = n0 + tx * 4;
    float v[4];
    #pragma unroll
    for (int j = 0; j < 4; ++j) v[j] = acc[i][j] + bias[nbase + j];
    if (RESID) {
      float4 r4 = *(const float4*)(R + (size_t)m * N + nbase);
      v[0] += r4.x; v[1] += r4.y; v[2] += r4.z; v[3] += r4.w;
    }
    if (RELU) {
      #pragma unroll
      for (int j = 0; j < 4; ++j) v[j] = fmaxf(v[j], 0.f);
    }
    float4 s4; s4.x = v[0]; s4.y = v[1]; s4.z = v[2]; s4.w = v[3];
    *(float4*)(C + (size_t)m * N + nbase) = s4;
  }
}

// ---------- in-place LayerNorm ----------
__global__ __launch_bounds__(256) void ln_k(float* h, const float* __restrict__ g, const float* __restrict__ bb)
{
  __shared__ float rs[256], rq[256];
  float* p = h + (size_t)blockIdx.x * 512;
  int t = threadIdx.x;
  float v0 = p[t], v1 = p[t + 256];
  rs[t] = v0 + v1; rq[t] = v0 * v0 + v1 * v1;
  __syncthreads();
  for (int o = 128; o > 0; o >>= 1) {
    if (t < o) { rs[t] += rs[t + o]; rq[t] += rq[t + o]; }
    __syncthreads();
  }
  float mean = rs[0] * (1.f / 512.f);
  float var = fmaxf(rq[0] * (1.f / 512.f) - mean * mean, 0.f);
  float rinv = rsqrtf(var + 1e-5f);
  p[t]       = (v0 - mean) * rinv * g[t]       + bb[t];
  p[t + 256] = (v1 - mean) * rinv * g[t + 256] + bb[t + 256];
}

// ---------- sparse block attention (global K/V, single LDS score buf) ----------
__global__ __launch_bounds__(128) void attn2_k(const float* __restrict__ qkv, float* __restrict__ av,
    const int* __restrict__ rnd, int S, int Sp, int nb)
{
  __shared__ float sS[8][80];
  __shared__ float sQ[8][64];
  __shared__ int sJB[10], sVD[10];
  int t = threadIdx.x;
  int n = blockIdx.x % nb;
  int r1 = blockIdx.x / nb;
  int hh = r1 & 7, b = r1 >> 3;
  const float* base = qkv + (size_t)b * Sp * 1536;

  if (t < 10) {
    int jb, vd;
    if (t < 2) { jb = t; vd = 1; }
    else if (t < 7) {
      int w = n + t - 4;
      vd = (w >= 0 && w < nb) ? 1 : 0;
      jb = w < 0 ? 0 : (w > nb - 1 ? nb - 1 : w);
    } else { jb = rnd[n * 3 + t - 7]; vd = 1; }
    sJB[t] = jb; sVD[t] = vd;
  }
  {
    int idx4 = t * 4;
    int qi = idx4 >> 6, c = idx4 & 63;
    const float* p = base + (size_t)(n * 8 + qi) * 1536 + hh * 64 + c;
    float4 u = *(const float4*)p;
    sQ[qi][c] = u.x; sQ[qi][c + 1] = u.y; sQ[qi][c + 2] = u.z; sQ[qi][c + 3] = u.w;
  }
  __syncthreads();
  if (t < 80) {
    int kb = t >> 3, kj = t & 7;
    int tok = sJB[kb] * 8 + kj;
    const float* kp = base + (size_t)tok * 1536 + 512 + hh * 64;
    bool ok = sVD[kb] && (tok < S);
    for (int qi = 0; qi < 8; ++qi) {
      float d = 0.f;
      for (int c = 0; c < 64; ++c) d += sQ[qi][c] * kp[c];
      sS[qi][t] = ok ? d * 0.125f : -1.0e9f;
    }
  }
  __syncthreads();
  if (t < 8) {
    float mx = -3.0e38f;
    for (int k = 0; k < 80; ++k) mx = fmaxf(mx, sS[t][k]);
    float sum = 0.f;
    for (int k = 0; k < 80; ++k) { float e = __expf(sS[t][k] - mx); sS[t][k] = e; sum += e; }
    float inv = 1.f / sum;
    for (int k = 0; k < 80; ++k) sS[t][k] *= inv;
  }
  __syncthreads();
  {
    int qi = t >> 4, dd = (t & 15) << 2;
    float o0 = 0, o1 = 0, o2 = 0, o3 = 0;
    for (int k = 0; k < 80; ++k) {
      float pp = sS[qi][k];
      int tok = sJB[k >> 3] * 8 + (k & 7);
      const float* vp = base + (size_t)tok * 1536 + 1024 + hh * 64 + dd;
      o0 += pp * vp[0]; o1 += pp * vp[1]; o2 += pp * vp[2]; o3 += pp * vp[3];
    }
    float4 u; u.x = o0; u.y = o1; u.z = o2; u.w = o3;
    *(float4*)(av + ((size_t)b * Sp + n * 8 + qi) * 512 + hh * 64 + dd) = u;
  }
}

// ---------- VAE head (fp32 elbo out) ----------
__global__ __launch_bounds__(512) void head_k(const float* __restrict__ h,
    const float* __restrict__ Wm, const float* __restrict__ bm,
    const float* __restrict__ Wlv, const float* __restrict__ blv,
    const float* __restrict__ eps, float* __restrict__ z, float* out_elbo)
{
  __shared__ float red[512];
  int t = threadIdx.x;
  int b = t >> 4, i = t & 15;
  const float* p = h + (size_t)b * SPENC * 512;
  float am = bm[i], al = blv[i];
  for (int c = 0; c < 512; ++c) {
    float pv = p[c];
    am += pv * Wm[c * 16 + i];
    al += pv * Wlv[c * 16 + i];
  }
  z[t] = am + eps[t] * expf(0.5f * al);
  red[t] = -0.5f * (1.f + al - am * am - expf(al));
  __syncthreads();
  for (int o = 256; o > 0; o >>= 1) { if (t < o) red[t] += red[t + o]; __syncthreads(); }
  if (t == 0) out_elbo[0] = red[0] * (1.f / 32.f);
}

// ---------- seq ----------
__global__ __launch_bounds__(256) void seq_k(const float* __restrict__ z, const float* __restrict__ We,
    const float* __restrict__ be, float* __restrict__ seq)
{
  int gid = blockIdx.x * 256 + threadIdx.x;
  int b = gid >> 11, c = gid & 2047;
  float acc = be[c];
  #pragma unroll
  for (int i = 0; i < 16; ++i) acc += z[b * 16 + i] * We[i * 2048 + c];
  seq[gid] = acc;
}

// ---------- decoder init ----------
__global__ __launch_bounds__(256) void decinit_k(const float* __restrict__ seq, const float* __restrict__ Wc,
    const float* __restrict__ bc, const float* __restrict__ emb, float* __restrict__ h)
{
  size_t gid = (size_t)blockIdx.x * 256 + threadIdx.x;
  int dd = (int)(gid & 511);
  size_t rs = gid >> 9;
  int s = (int)(rs & 1023);
  int b = (int)(rs >> 10);
  float v = seq[b * 2048 + s] * Wc[dd] + seq[b * 2048 + 1024 + s] * Wc[512 + dd]
          + bc[dd] + emb[(size_t)s * 512 + dd];
  h[gid] = v;
}

// ---------- final (fp32 out) ----------
__global__ __launch_bounds__(256) void final_k(const float* __restrict__ h, const float* __restrict__ Ws,
    const float* __restrict__ bs, float* __restrict__ out)
{
  int gid = blockIdx.x * 256 + threadIdx.x;
  int nn = gid & 15;
  int rs = gid >> 4;
  const float* p = h + (size_t)rs * 512;
  float acc = bs[nn];
  for (int c = 0; c < 512; ++c) acc += p[c] * Ws[c * 16 + nn];
  out[gid] = acc;
}

extern "C" void kernel_launch(void* const* d_in, const int* in_sizes, int n_in,
                              void* d_out, int out_size, void* d_ws, size_t ws_size,
                              hipStream_t stream) {
  float* out = (float*)d_out;
  (void)out_size; (void)ws_size;

  // ---- input-order verification (dict order confirmed in round 5; beacon = safety net) ----
  static const int EXP_DICT[30] = {
    524288, 512, 524800, 524288, 8192, 512, 7864320, 15360, 2621440, 5120,
    5120, 5120, 10485760, 20480, 10485760, 5120, 5120, 5120, 8192, 16,
    8192, 16, 32768, 2048, 1024, 512, 8192, 16, 387, 384 };
  bool dict_ok = (n_in == 30);
  if (dict_ok) for (int i = 0; i < 30; ++i) if (in_sizes[i] != EXP_DICT[i]) { dict_ok = false; break; }
  if (!dict_ok) { beacon_k<<<1, 64, 0, stream>>>(out); return; }

  const float* x      = (const float*)d_in[0];
  const float* eps    = (const float*)d_in[1];
  const float* emb_in = (const float*)d_in[2];
  const float* emb_out= (const float*)d_in[3];
  const float* W_data = (const float*)d_in[4];
  const float* b_data = (const float*)d_in[5];
  const float* Wqkv   = (const float*)d_in[6];
  const float* bqkv   = (const float*)d_in[7];
  const float* Wo     = (const float*)d_in[8];
  const float* bo     = (const float*)d_in[9];
  const float* ln1g   = (const float*)d_in[10];
  const float* ln1b   = (const float*)d_in[11];
  const float* W1     = (const float*)d_in[12];
  const float* b1     = (const float*)d_in[13];
  const float* W2     = (const float*)d_in[14];
  const float* b2     = (const float*)d_in[15];
  const float* ln2g   = (const float*)d_in[16];
  const float* ln2b   = (const float*)d_in[17];
  const float* Wm     = (const float*)d_in[18];
  const float* bm     = (const float*)d_in[19];
  const float* Wlv    = (const float*)d_in[20];
  const float* blv    = (const float*)d_in[21];
  const float* Wexp   = (const float*)d_in[22];
  const float* bexp   = (const float*)d_in[23];
  const float* Wconv  = (const float*)d_in[24];
  const float* bconv  = (const float*)d_in[25];
  const float* Wseq   = (const float*)d_in[26];
  const float* bseq   = (const float*)d_in[27];
  const int* rand_enc = (const int*)d_in[28];
  const int* rand_dec = (const int*)d_in[29];

  // ---- workspace carve (~135.5 MB) ----
  char* ws = (char*)d_ws;
  float* h    = (float*)ws;                                  // MENC*512 f32
  float* big  = (float*)(ws + 67633152);                     // transient union
  float* qkvb = big;                                         // 8*1032*1536 f32
  float* avb  = big + 12681216;                              // 8*1032*512 f32
  float* ffnb = big;                                         // 8192*2048 f32 (union)
  float* seq  = (float*)(ws + 67633152 + 67633152);
  float* z    = (float*)(ws + 67633152 + 67633152 + 262144);

  // ===== encoder =====
  {
    const int M = MENC;
    embed_k<<<(M * 512) / 256, 256, 0, stream>>>(x, W_data, b_data, emb_in, h);
    for (int i = 0; i < 5; ++i) {
      for (int bc = 0; bc < 4; ++bc) {
        float* hc = h + (size_t)bc * 8 * SPENC * 512;
        const int Mc = 8 * SPENC;
        gemm_k<false, false><<<dim3(1536 / 64, Mc / 64), 256, 0, stream>>>(
            hc, Wqkv + (size_t)i * 512 * 1536, bqkv + (size_t)i * 1536, nullptr, qkvb, Mc, 1536, 512);
        attn2_k<<<8 * 8 * NBE, 128, 0, stream>>>(qkvb, avb, rand_enc, SENC, SPENC, NBE);
        gemm_k<false, true><<<dim3(512 / 64, Mc / 64), 256, 0, stream>>>(
            avb, Wo + (size_t)i * 512 * 512, bo + (size_t)i * 512, hc, hc, Mc, 512, 512);
      }
      ln_k<<<M, 256, 0, stream>>>(h, ln1g + (size_t)i * 512, ln1b + (size_t)i * 512);
      for (int off = 0; off < M; off += 8192) {
        int Mc = (M - off < 8192) ? (M - off) : 8192;
        gemm_k<true, false><<<dim3(2048 / 64, Mc / 64), 256, 0, stream>>>(
            h + (size_t)off * 512, W1 + (size_t)i * 512 * 2048, b1 + (size_t)i * 2048, nullptr, ffnb, Mc, 2048, 512);
        gemm_k<false, true><<<dim3(512 / 64, Mc / 64), 256, 0, stream>>>(
            ffnb, W2 + (size_t)i * 2048 * 512, b2 + (size_t)i * 512, h + (size_t)off * 512, h + (size_t)off * 512, Mc, 512, 2048);
      }
      ln_k<<<M, 256, 0, stream>>>(h, ln2g + (size_t)i * 512, ln2b + (size_t)i * 512);
    }
  }

  // ===== VAE head =====
  head_k<<<1, 512, 0, stream>>>(h, Wm, bm, Wlv, blv, eps, z, out + 524288);
  seq_k<<<256, 256, 0, stream>>>(z, Wexp, bexp, seq);
  decinit_k<<<(MDEC * 512) / 256, 256, 0, stream>>>(seq, Wconv, bconv, emb_out, h);

  // ===== decoder =====
  {
    const int M = MDEC;
    for (int i = 5; i < 10; ++i) {
      for (int bc = 0; bc < 4; ++bc) {
        float* hc = h + (size_t)bc * 8 * SDEC * 512;
        const int Mc = 8 * SDEC;
        gemm_k<false, false><<<dim3(1536 / 64, Mc / 64), 256, 0, stream>>>(
            hc, Wqkv + (size_t)i * 512 * 1536, bqkv + (size_t)i * 1536, nullptr, qkvb, Mc, 1536, 512);
        attn2_k<<<8 * 8 * NBD, 128, 0, stream>>>(qkvb, avb, rand_dec, SDEC, SDEC, NBD);
        gemm_k<false, true><<<dim3(512 / 64, Mc / 64), 256, 0, stream>>>(
            avb, Wo + (size_t)i * 512 * 512, bo + (size_t)i * 512, hc, hc, Mc, 512, 512);
      }
      ln_k<<<M, 256, 0, stream>>>(h, ln1g + (size_t)i * 512, ln1b + (size_t)i * 512);
      for (int off = 0; off < M; off += 8192) {
        int Mc = 8192;
        gemm_k<true, false><<<dim3(2048 / 64, Mc / 64), 256, 0, stream>>>(
            h + (size_t)off * 512, W1 + (size_t)i * 512 * 2048, b1 + (size_t)i * 2048, nullptr, ffnb, Mc, 2048, 512);
        gemm_k<false, true><<<dim3(512 / 64, Mc / 64), 256, 0, stream>>>(
            ffnb, W2 + (size_t)i * 2048 * 512, b2 + (size_t)i * 512, h + (size_t)off * 512, h + (size_t)off * 512, Mc, 512, 2048);
      }
      ln_k<<<M, 256, 0, stream>>>(h, ln2g + (size_t)i * 512, ln2b + (size_t)i * 512);
    }
  }

  // ===== output =====
  final_k<<<524288 / 256, 256, 0, stream>>>(h, Wseq, bseq, out);
}

// Round 7
// 14257.648 us; speedup vs baseline: 2.3856x; 2.3856x over previous
//
#include <hip/hip_runtime.h>

typedef unsigned short u16;
typedef __attribute__((ext_vector_type(8))) short short8;
typedef __attribute__((ext_vector_type(4))) float f32x4;

__device__ __forceinline__ float b2f(u16 h) {
  union { unsigned int u; float f; } v; v.u = ((unsigned int)h) << 16; return v.f;
}
__device__ __forceinline__ u16 f2b(float f) {
  union { float f; unsigned int u; } v; v.f = f;
  return (u16)((v.u + 0x7fffu + ((v.u >> 16) & 1u)) >> 16);
}

#define SENC 1025
#define SPENC 1032
#define NBE 129
#define SDEC 1024
#define NBD 128
#define BATCH 32
#define MENC (BATCH * SPENC)  /* 33024 */
#define MDEC (BATCH * SDEC)   /* 32768 */
#define LDK 40                /* padded LDS row length (bf16 units) */

// ---------- beacon ----------
__global__ void beacon_k(float* out) { if (threadIdx.x == 0) out[0] = 1000.0f; }

// ---------- weight transpose + bf16 convert: WT[n][k] = bf16(W[k][n]), per layer (z) ----------
__global__ __launch_bounds__(256) void tr_k(const float* __restrict__ W, u16* __restrict__ WT, int K, int N)
{
  __shared__ float sm[32][33];
  int k0 = blockIdx.x * 32, n0 = blockIdx.y * 32;
  const float* Wz = W + (size_t)blockIdx.z * K * N;
  u16* WTz = WT + (size_t)blockIdx.z * K * N;
  int r = threadIdx.x >> 3, c0 = (threadIdx.x & 7) * 4;
  float4 v = *(const float4*)&Wz[(size_t)(k0 + r) * N + n0 + c0];
  sm[r][c0] = v.x; sm[r][c0 + 1] = v.y; sm[r][c0 + 2] = v.z; sm[r][c0 + 3] = v.w;
  __syncthreads();
  ushort4 u;
  u.x = f2b(sm[c0][r]); u.y = f2b(sm[c0 + 1][r]); u.z = f2b(sm[c0 + 2][r]); u.w = f2b(sm[c0 + 3][r]);
  *(ushort4*)&WTz[(size_t)(n0 + r) * K + k0 + c0] = u;
}

// ---------- embed: h fp32 + hb bf16 ----------
__global__ __launch_bounds__(256) void embed_k(const float* __restrict__ x, const float* __restrict__ Wd,
    const float* __restrict__ bd, const float* __restrict__ emb, float* __restrict__ h, u16* __restrict__ hb)
{
  size_t gid = (size_t)blockIdx.x * 256 + threadIdx.x;  // MENC*512
  int dd = (int)(gid & 511);
  size_t rs = gid >> 9;
  int s = (int)(rs % SPENC);
  int b = (int)(rs / SPENC);
  float v;
  if (s == 0) {
    v = emb[dd];
  } else if (s < SENC) {
    float acc = bd[dd];
    const float* xr = x + ((size_t)b * 1024 + (s - 1)) * 16;
    #pragma unroll
    for (int j = 0; j < 16; ++j) acc += xr[j] * Wd[j * 512 + dd];
    v = acc + emb[(size_t)s * 512 + dd];
  } else {
    v = 0.f;
  }
  h[gid] = v;
  hb[gid] = f2b(v);
}

// ---------- MFMA bf16 GEMM: C[M,N] = A[M,K](bf16) @ WT[N,K]^T (bf16) + bias(f32) (+R f32)(ReLU) ----------
template<typename TC, bool RELU, bool RESID>
__global__ __launch_bounds__(256) void mgemm_k(const u16* __restrict__ A, const u16* __restrict__ WT,
    const float* __restrict__ bias, const float* __restrict__ R, TC* __restrict__ C,
    int M, int N, int K, int lda)
{
  __shared__ u16 sA[128 * LDK];
  __shared__ u16 sB[128 * LDK];
  int t = threadIdx.x;
  int n0 = blockIdx.x * 128, m0 = blockIdx.y * 128;
  int lane = t & 63, wave = t >> 6;
  int wm = (wave >> 1) * 64, wn = (wave & 1) * 64;
  int quad = lane >> 4, l15 = lane & 15;

  // staging: thread t handles rows (t>>2) and (t>>2)+64, 8-elem chunk (t&3)*8
  int sr = t >> 2;
  int so = (t & 3) * 8;
  int am0 = m0 + sr, am1 = m0 + sr + 64;
  int ca0 = am0 < M ? am0 : M - 1;
  int ca1 = am1 < M ? am1 : M - 1;
  const u16* Ap0 = A + (size_t)ca0 * lda + so;
  const u16* Ap1 = A + (size_t)ca1 * lda + so;
  const u16* Bp0 = WT + (size_t)(n0 + sr) * K + so;
  const u16* Bp1 = WT + (size_t)(n0 + sr + 64) * K + so;
  u16* dA0 = &sA[sr * LDK + so];       u16* dA1 = &sA[(sr + 64) * LDK + so];
  u16* dB0 = &sB[sr * LDK + so];       u16* dB1 = &sB[(sr + 64) * LDK + so];

  f32x4 acc[4][4];
  #pragma unroll
  for (int i = 0; i < 4; ++i)
    #pragma unroll
    for (int j = 0; j < 4; ++j) acc[i][j] = (f32x4){0.f, 0.f, 0.f, 0.f};

  for (int k0 = 0; k0 < K; k0 += 32) {
    short8 a0 = *(const short8*)(Ap0 + k0);
    short8 a1 = *(const short8*)(Ap1 + k0);
    short8 b0 = *(const short8*)(Bp0 + k0);
    short8 b1 = *(const short8*)(Bp1 + k0);
    __syncthreads();
    *(short8*)dA0 = a0; *(short8*)dA1 = a1;
    *(short8*)dB0 = b0; *(short8*)dB1 = b1;
    __syncthreads();
    short8 af[4], bf[4];
    #pragma unroll
    for (int i = 0; i < 4; ++i) af[i] = *(const short8*)&sA[(wm + i * 16 + l15) * LDK + quad * 8];
    #pragma unroll
    for (int j = 0; j < 4; ++j) bf[j] = *(const short8*)&sB[(wn + j * 16 + l15) * LDK + quad * 8];
    #pragma unroll
    for (int i = 0; i < 4; ++i)
      #pragma unroll
      for (int j = 0; j < 4; ++j)
        acc[i][j] = __builtin_amdgcn_mfma_f32_16x16x32_bf16(af[i], bf[j], acc[i][j], 0, 0, 0);
  }

  // epilogue: D row = quad*4+reg (m), col = lane&15 (n)  [m89-verified]
  #pragma unroll
  for (int i = 0; i < 4; ++i) {
    int mBase = m0 + wm + i * 16 + quad * 4;
    #pragma unroll
    for (int r = 0; r < 4; ++r) {
      int m = mBase + r;
      if (m < M) {
        #pragma unroll
        for (int j = 0; j < 4; ++j) {
          int n = n0 + wn + j * 16 + l15;
          float v = acc[i][j][r] + bias[n];
          if (RESID) v += R[(size_t)m * N + n];
          if (RELU) v = fmaxf(v, 0.f);
          if constexpr (sizeof(TC) == 2) ((u16*)C)[(size_t)m * N + n] = f2b(v);
          else ((float*)C)[(size_t)m * N + n] = v;
        }
      }
    }
  }
}

// ---------- in-place LayerNorm, also emits bf16 shadow ----------
__global__ __launch_bounds__(256) void ln_k(float* h, u16* __restrict__ hb,
    const float* __restrict__ g, const float* __restrict__ bb)
{
  __shared__ float rs[256], rq[256];
  float* p = h + (size_t)blockIdx.x * 512;
  u16* pb = hb + (size_t)blockIdx.x * 512;
  int t = threadIdx.x;
  float v0 = p[t], v1 = p[t + 256];
  rs[t] = v0 + v1; rq[t] = v0 * v0 + v1 * v1;
  __syncthreads();
  for (int o = 128; o > 0; o >>= 1) {
    if (t < o) { rs[t] += rs[t + o]; rq[t] += rq[t + o]; }
    __syncthreads();
  }
  float mean = rs[0] * (1.f / 512.f);
  float var = fmaxf(rq[0] * (1.f / 512.f) - mean * mean, 0.f);
  float rinv = rsqrtf(var + 1e-5f);
  float o0 = (v0 - mean) * rinv * g[t] + bb[t];
  float o1 = (v1 - mean) * rinv * g[t + 256] + bb[t + 256];
  p[t] = o0; p[t + 256] = o1;
  pb[t] = f2b(o0); pb[t + 256] = f2b(o1);
}

// ---------- sparse block attention (bf16 qkv in, bf16 av out) ----------
__global__ __launch_bounds__(128) void attnb_k(const u16* __restrict__ qkv, u16* __restrict__ av,
    const int* __restrict__ rnd, int S, int Sp, int nb)
{
  __shared__ float sS[8][80];
  __shared__ float sQ[8][64];
  __shared__ int sJB[10], sVD[10];
  int t = threadIdx.x;
  int n = blockIdx.x % nb;
  int r1 = blockIdx.x / nb;
  int hh = r1 & 7, b = r1 >> 3;
  const u16* base = qkv + (size_t)b * Sp * 1536;

  if (t < 10) {
    int jb, vd;
    if (t < 2) { jb = t; vd = 1; }
    else if (t < 7) {
      int w = n + t - 4;
      vd = (w >= 0 && w < nb) ? 1 : 0;
      jb = w < 0 ? 0 : (w > nb - 1 ? nb - 1 : w);
    } else { jb = rnd[n * 3 + t - 7]; vd = 1; }
    sJB[t] = jb; sVD[t] = vd;
  }
  {
    int idx4 = t * 4;
    int qi = idx4 >> 6, c = idx4 & 63;
    ushort4 u = *(const ushort4*)(base + (size_t)(n * 8 + qi) * 1536 + hh * 64 + c);
    sQ[qi][c] = b2f(u.x); sQ[qi][c + 1] = b2f(u.y); sQ[qi][c + 2] = b2f(u.z); sQ[qi][c + 3] = b2f(u.w);
  }
  __syncthreads();
  if (t < 80) {
    int kb = t >> 3, kj = t & 7;
    int tok = sJB[kb] * 8 + kj;
    const u16* kp = base + (size_t)tok * 1536 + 512 + hh * 64;
    bool ok = sVD[kb] && (tok < S);
    float d8[8];
    #pragma unroll
    for (int qi = 0; qi < 8; ++qi) d8[qi] = 0.f;
    for (int c = 0; c < 64; c += 4) {
      ushort4 u = *(const ushort4*)(kp + c);
      float k0 = b2f(u.x), k1 = b2f(u.y), k2 = b2f(u.z), k3 = b2f(u.w);
      #pragma unroll
      for (int qi = 0; qi < 8; ++qi)
        d8[qi] += sQ[qi][c] * k0 + sQ[qi][c + 1] * k1 + sQ[qi][c + 2] * k2 + sQ[qi][c + 3] * k3;
    }
    #pragma unroll
    for (int qi = 0; qi < 8; ++qi) sS[qi][t] = ok ? d8[qi] * 0.125f : -1.0e9f;
  }
  __syncthreads();
  if (t < 8) {
    float mx = -3.0e38f;
    for (int k = 0; k < 80; ++k) mx = fmaxf(mx, sS[t][k]);
    float sum = 0.f;
    for (int k = 0; k < 80; ++k) { float e = __expf(sS[t][k] - mx); sS[t][k] = e; sum += e; }
    float inv = 1.f / sum;
    for (int k = 0; k < 80; ++k) sS[t][k] *= inv;
  }
  __syncthreads();
  {
    int qi = t >> 4, dd = (t & 15) << 2;
    float o0 = 0, o1 = 0, o2 = 0, o3 = 0;
    for (int k = 0; k < 80; ++k) {
      float pp = sS[qi][k];
      int tok = sJB[k >> 3] * 8 + (k & 7);
      ushort4 u = *(const ushort4*)(base + (size_t)tok * 1536 + 1024 + hh * 64 + dd);
      o0 += pp * b2f(u.x); o1 += pp * b2f(u.y); o2 += pp * b2f(u.z); o3 += pp * b2f(u.w);
    }
    ushort4 u; u.x = f2b(o0); u.y = f2b(o1); u.z = f2b(o2); u.w = f2b(o3);
    *(ushort4*)(av + ((size_t)b * Sp + n * 8 + qi) * 512 + hh * 64 + dd) = u;
  }
}

// ---------- VAE head ----------
__global__ __launch_bounds__(512) void head_k(const float* __restrict__ h,
    const float* __restrict__ Wm, const float* __restrict__ bm,
    const float* __restrict__ Wlv, const float* __restrict__ blv,
    const float* __restrict__ eps, float* __restrict__ z, float* out_elbo)
{
  __shared__ float red[512];
  int t = threadIdx.x;
  int b = t >> 4, i = t & 15;
  const float* p = h + (size_t)b * SPENC * 512;
  float am = bm[i], al = blv[i];
  for (int c = 0; c < 512; ++c) {
    float pv = p[c];
    am += pv * Wm[c * 16 + i];
    al += pv * Wlv[c * 16 + i];
  }
  z[t] = am + eps[t] * expf(0.5f * al);
  red[t] = -0.5f * (1.f + al - am * am - expf(al));
  __syncthreads();
  for (int o = 256; o > 0; o >>= 1) { if (t < o) red[t] += red[t + o]; __syncthreads(); }
  if (t == 0) out_elbo[0] = red[0] * (1.f / 32.f);
}

// ---------- seq ----------
__global__ __launch_bounds__(256) void seq_k(const float* __restrict__ z, const float* __restrict__ We,
    const float* __restrict__ be, float* __restrict__ seq)
{
  int gid = blockIdx.x * 256 + threadIdx.x;
  int b = gid >> 11, c = gid & 2047;
  float acc = be[c];
  #pragma unroll
  for (int i = 0; i < 16; ++i) acc += z[b * 16 + i] * We[i * 2048 + c];
  seq[gid] = acc;
}

// ---------- decoder init: h fp32 + hb bf16 ----------
__global__ __launch_bounds__(256) void decinit_k(const float* __restrict__ seq, const float* __restrict__ Wc,
    const float* __restrict__ bc, const float* __restrict__ emb, float* __restrict__ h, u16* __restrict__ hb)
{
  size_t gid = (size_t)blockIdx.x * 256 + threadIdx.x;
  int dd = (int)(gid & 511);
  size_t rs = gid >> 9;
  int s = (int)(rs & 1023);
  int b = (int)(rs >> 10);
  float v = seq[b * 2048 + s] * Wc[dd] + seq[b * 2048 + 1024 + s] * Wc[512 + dd]
          + bc[dd] + emb[(size_t)s * 512 + dd];
  h[gid] = v;
  hb[gid] = f2b(v);
}

// ---------- final ----------
__global__ __launch_bounds__(256) void final_k(const float* __restrict__ h, const float* __restrict__ Ws,
    const float* __restrict__ bs, float* __restrict__ out)
{
  int gid = blockIdx.x * 256 + threadIdx.x;
  int nn = gid & 15;
  int rs = gid >> 4;
  const float* p = h + (size_t)rs * 512;
  float acc = bs[nn];
  for (int c = 0; c < 512; ++c) acc += p[c] * Ws[c * 16 + nn];
  out[gid] = acc;
}

extern "C" void kernel_launch(void* const* d_in, const int* in_sizes, int n_in,
                              void* d_out, int out_size, void* d_ws, size_t ws_size,
                              hipStream_t stream) {
  float* out = (float*)d_out;
  (void)out_size; (void)ws_size;

  static const int EXP_DICT[30] = {
    524288, 512, 524800, 524288, 8192, 512, 7864320, 15360, 2621440, 5120,
    5120, 5120, 10485760, 20480, 10485760, 5120, 5120, 5120, 8192, 16,
    8192, 16, 32768, 2048, 1024, 512, 8192, 16, 387, 384 };
  bool dict_ok = (n_in == 30);
  if (dict_ok) for (int i = 0; i < 30; ++i) if (in_sizes[i] != EXP_DICT[i]) { dict_ok = false; break; }
  if (!dict_ok) { beacon_k<<<1, 64, 0, stream>>>(out); return; }

  const float* x      = (const float*)d_in[0];
  const float* eps    = (const float*)d_in[1];
  const float* emb_in = (const float*)d_in[2];
  const float* emb_out= (const float*)d_in[3];
  const float* W_data = (const float*)d_in[4];
  const float* b_data = (const float*)d_in[5];
  const float* Wqkv   = (const float*)d_in[6];
  const float* bqkv   = (const float*)d_in[7];
  const float* Wo     = (const float*)d_in[8];
  const float* bo     = (const float*)d_in[9];
  const float* ln1g   = (const float*)d_in[10];
  const float* ln1b   = (const float*)d_in[11];
  const float* W1     = (const float*)d_in[12];
  const float* b1     = (const float*)d_in[13];
  const float* W2     = (const float*)d_in[14];
  const float* b2     = (const float*)d_in[15];
  const float* ln2g   = (const float*)d_in[16];
  const float* ln2b   = (const float*)d_in[17];
  const float* Wm     = (const float*)d_in[18];
  const float* bm     = (const float*)d_in[19];
  const float* Wlv    = (const float*)d_in[20];
  const float* blv    = (const float*)d_in[21];
  const float* Wexp   = (const float*)d_in[22];
  const float* bexp   = (const float*)d_in[23];
  const float* Wconv  = (const float*)d_in[24];
  const float* bconv  = (const float*)d_in[25];
  const float* Wseq   = (const float*)d_in[26];
  const float* bseq   = (const float*)d_in[27];
  const int* rand_enc = (const int*)d_in[28];
  const int* rand_dec = (const int*)d_in[29];

  // ---- workspace carve (~181.3 MB) ----
  char* ws = (char*)d_ws;
  float* h     = (float*)ws;                         // 67,633,152 B
  u16*   hb    = (u16*)(ws + 67633152);              // 33,816,576 B
  u16*   WTqkv = (u16*)(ws + 101449728);             // 15,728,640 B
  u16*   WTo   = (u16*)(ws + 117178368);             //  5,242,880 B
  u16*   WT1   = (u16*)(ws + 122421248);             // 20,971,520 B
  u16*   WT2   = (u16*)(ws + 143392768);             // 20,971,520 B
  u16*   qkvb  = (u16*)(ws + 164364288);             // 12,681,216 B (chunk: 4*1032*1536 bf16)
  u16*   avb   = (u16*)(ws + 177045504);             //  4,227,072 B
  u16*   ffnb  = (u16*)(ws + 164364288);             // 16,777,216 B (union with qkvb/avb)
  float* seqb  = (float*)(ws + 181272576);           //    262,144 B
  float* z     = (float*)(ws + 181534720);           //      2,048 B

  // ---- weight transpose+convert (every call; ws is re-poisoned) ----
  tr_k<<<dim3(512 / 32, 1536 / 32, 10), 256, 0, stream>>>(Wqkv, WTqkv, 512, 1536);
  tr_k<<<dim3(512 / 32, 512 / 32, 10), 256, 0, stream>>>(Wo, WTo, 512, 512);
  tr_k<<<dim3(512 / 32, 2048 / 32, 10), 256, 0, stream>>>(W1, WT1, 512, 2048);
  tr_k<<<dim3(2048 / 32, 512 / 32, 10), 256, 0, stream>>>(W2, WT2, 2048, 512);

  // ===== encoder: M=33024; attention in 8 chunks of 4 batches (Mc=4128) =====
  {
    const int M = MENC;
    embed_k<<<(M * 512) / 256, 256, 0, stream>>>(x, W_data, b_data, emb_in, h, hb);
    for (int i = 0; i < 5; ++i) {
      for (int bc = 0; bc < 8; ++bc) {
        size_t roff = (size_t)bc * 4 * SPENC * 512;
        const int Mc = 4 * SPENC;  // 4128
        mgemm_k<u16, false, false><<<dim3(1536 / 128, 33), 256, 0, stream>>>(
            hb + roff, WTqkv + (size_t)i * 512 * 1536, bqkv + (size_t)i * 1536, nullptr, qkvb, Mc, 1536, 512, 512);
        attnb_k<<<4 * 8 * NBE, 128, 0, stream>>>(qkvb, avb, rand_enc, SENC, SPENC, NBE);
        mgemm_k<float, false, true><<<dim3(512 / 128, 33), 256, 0, stream>>>(
            avb, WTo + (size_t)i * 512 * 512, bo + (size_t)i * 512, h + roff, h + roff, Mc, 512, 512, 512);
      }
      ln_k<<<M, 256, 0, stream>>>(h, hb, ln1g + (size_t)i * 512, ln1b + (size_t)i * 512);
      for (int off = 0; off < M; off += 4096) {
        int Mc = (M - off < 4096) ? (M - off) : 4096;
        int ty = (Mc + 127) / 128;
        mgemm_k<u16, true, false><<<dim3(2048 / 128, ty), 256, 0, stream>>>(
            hb + (size_t)off * 512, WT1 + (size_t)i * 512 * 2048, b1 + (size_t)i * 2048, nullptr, ffnb, Mc, 2048, 512, 512);
        mgemm_k<float, false, true><<<dim3(512 / 128, ty), 256, 0, stream>>>(
            ffnb, WT2 + (size_t)i * 2048 * 512, b2 + (size_t)i * 512, h + (size_t)off * 512, h + (size_t)off * 512, Mc, 512, 2048, 2048);
      }
      ln_k<<<M, 256, 0, stream>>>(h, hb, ln2g + (size_t)i * 512, ln2b + (size_t)i * 512);
    }
  }

  // ===== VAE head =====
  head_k<<<1, 512, 0, stream>>>(h, Wm, bm, Wlv, blv, eps, z, out + 524288);
  seq_k<<<256, 256, 0, stream>>>(z, Wexp, bexp, seqb);
  decinit_k<<<(MDEC * 512) / 256, 256, 0, stream>>>(seqb, Wconv, bconv, emb_out, h, hb);

  // ===== decoder: M=32768; attention in 8 chunks of 4 batches (Mc=4096) =====
  {
    const int M = MDEC;
    for (int i = 5; i < 10; ++i) {
      for (int bc = 0; bc < 8; ++bc) {
        size_t roff = (size_t)bc * 4 * SDEC * 512;
        const int Mc = 4 * SDEC;  // 4096
        mgemm_k<u16, false, false><<<dim3(1536 / 128, 32), 256, 0, stream>>>(
            hb + roff, WTqkv + (size_t)i * 512 * 1536, bqkv + (size_t)i * 1536, nullptr, qkvb, Mc, 1536, 512, 512);
        attnb_k<<<4 * 8 * NBD, 128, 0, stream>>>(qkvb, avb, rand_dec, SDEC, SDEC, NBD);
        mgemm_k<float, false, true><<<dim3(512 / 128, 32), 256, 0, stream>>>(
            avb, WTo + (size_t)i * 512 * 512, bo + (size_t)i * 512, h + roff, h + roff, Mc, 512, 512, 512);
      }
      ln_k<<<M, 256, 0, stream>>>(h, hb, ln1g + (size_t)i * 512, ln1b + (size_t)i * 512);
      for (int off = 0; off < M; off += 4096) {
        const int Mc = 4096;
        mgemm_k<u16, true, false><<<dim3(2048 / 128, 32), 256, 0, stream>>>(
            hb + (size_t)off * 512, WT1 + (size_t)i * 512 * 2048, b1 + (size_t)i * 2048, nullptr, ffnb, Mc, 2048, 512, 512);
        mgemm_k<float, false, true><<<dim3(512 / 128, 32), 256, 0, stream>>>(
            ffnb, WT2 + (size_t)i * 2048 * 512, b2 + (size_t)i * 512, h + (size_t)off * 512, h + (size_t)off * 512, Mc, 512, 2048, 2048);
      }
      ln_k<<<M, 256, 0, stream>>>(h, hb, ln2g + (size_t)i * 512, ln2b + (size_t)i * 512);
    }
  }

  // ===== output =====
  final_k<<<524288 / 256, 256, 0, stream>>>(h, Wseq, bseq, out);
}

// Round 8
// 10539.681 us; speedup vs baseline: 3.2272x; 1.3528x over previous
//
#include <hip/hip_runtime.h>

typedef unsigned short u16;
typedef __attribute__((ext_vector_type(8))) short short8;
typedef __attribute__((ext_vector_type(4))) float f32x4;

__device__ __forceinline__ float b2f(u16 h) {
  union { unsigned int u; float f; } v; v.u = ((unsigned int)h) << 16; return v.f;
}
__device__ __forceinline__ u16 f2b(float f) {
  union { float f; unsigned int u; } v; v.f = f;
  return (u16)((v.u + 0x7fffu + ((v.u >> 16) & 1u)) >> 16);
}

// async global->LDS, 16B per lane; dst must be wave-base + lane*16 (m97 pattern)
__device__ __forceinline__ void gload16(const u16* g, u16* l) {
  __builtin_amdgcn_global_load_lds(
      (const __attribute__((address_space(1))) void*)g,
      (__attribute__((address_space(3))) void*)l, 16, 0, 0);
}

#define SENC 1025
#define SPENC 1032
#define NBE 129
#define SDEC 1024
#define NBD 128
#define BATCH 32
#define MENC (BATCH * SPENC)  /* 33024 */
#define MDEC (BATCH * SDEC)   /* 32768 */

// ---------- beacon ----------
__global__ void beacon_k(float* out) { if (threadIdx.x == 0) out[0] = 1000.0f; }

// ---------- weight transpose + bf16 convert: WT[n][k] = bf16(W[k][n]) ----------
__global__ __launch_bounds__(256) void tr_k(const float* __restrict__ W, u16* __restrict__ WT, int K, int N)
{
  __shared__ float sm[32][33];
  int k0 = blockIdx.x * 32, n0 = blockIdx.y * 32;
  const float* Wz = W + (size_t)blockIdx.z * K * N;
  u16* WTz = WT + (size_t)blockIdx.z * K * N;
  int r = threadIdx.x >> 3, c0 = (threadIdx.x & 7) * 4;
  float4 v = *(const float4*)&Wz[(size_t)(k0 + r) * N + n0 + c0];
  sm[r][c0] = v.x; sm[r][c0 + 1] = v.y; sm[r][c0 + 2] = v.z; sm[r][c0 + 3] = v.w;
  __syncthreads();
  ushort4 u;
  u.x = f2b(sm[c0][r]); u.y = f2b(sm[c0 + 1][r]); u.z = f2b(sm[c0 + 2][r]); u.w = f2b(sm[c0 + 3][r]);
  *(ushort4*)&WTz[(size_t)(n0 + r) * K + k0 + c0] = u;
}

// ---------- embed: h fp32 + hb bf16 ----------
__global__ __launch_bounds__(256) void embed_k(const float* __restrict__ x, const float* __restrict__ Wd,
    const float* __restrict__ bd, const float* __restrict__ emb, float* __restrict__ h, u16* __restrict__ hb)
{
  size_t gid = (size_t)blockIdx.x * 256 + threadIdx.x;  // MENC*512
  int dd = (int)(gid & 511);
  size_t rs = gid >> 9;
  int s = (int)(rs % SPENC);
  int b = (int)(rs / SPENC);
  float v;
  if (s == 0) {
    v = emb[dd];
  } else if (s < SENC) {
    float acc = bd[dd];
    const float* xr = x + ((size_t)b * 1024 + (s - 1)) * 16;
    #pragma unroll
    for (int j = 0; j < 16; ++j) acc += xr[j] * Wd[j * 512 + dd];
    v = acc + emb[(size_t)s * 512 + dd];
  } else {
    v = 0.f;
  }
  h[gid] = v;
  hb[gid] = f2b(v);
}

// ---------- MFMA bf16 GEMM with global_load_lds + XOR-swizzled LDS ----------
// C[M,N] = A[M,K](bf16) @ WT[N,K]^T(bf16) + bias(f32) (+R f32)(ReLU opt)
// LDS chunk (16B = 8 bf16): logical k-chunk c of row r stored at slot r*4 + (c ^ ((r>>1)&3))
template<typename TC, bool RELU, bool RESID>
__global__ __launch_bounds__(256) void mgemm_k(const u16* __restrict__ A, const u16* __restrict__ WT,
    const float* __restrict__ bias, const float* __restrict__ R, TC* __restrict__ C,
    int M, int N, int K, int lda)
{
  __shared__ __align__(16) u16 sA[128 * 32];
  __shared__ __align__(16) u16 sB[128 * 32];
  int t = threadIdx.x;
  int n0 = blockIdx.x * 128, m0 = blockIdx.y * 128;
  int lane = t & 63, wave = t >> 6;
  int wm = (wave >> 1) * 64, wn = (wave & 1) * 64;
  int quad = lane >> 4, l15 = lane & 15;

  // staging: issue j in {0,1}: LDS chunk Lc = wave*128 + j*64 + lane (lane-contiguous per wave)
  int r0 = wave * 32 + (lane >> 2);   // row for issue 0
  int r1 = r0 + 16;                    // row for issue 1
  int sc = lane & 3;                   // stored chunk slot
  int c0 = sc ^ ((r0 >> 1) & 3);       // logical k-chunk fetched into slot
  int c1 = sc ^ ((r1 >> 1) & 3);
  int ra0 = m0 + r0; ra0 = ra0 < M ? ra0 : M - 1;
  int ra1 = m0 + r1; ra1 = ra1 < M ? ra1 : M - 1;
  const u16* gA0 = A + (size_t)ra0 * lda + c0 * 8;
  const u16* gA1 = A + (size_t)ra1 * lda + c1 * 8;
  const u16* gB0 = WT + (size_t)(n0 + r0) * K + c0 * 8;
  const u16* gB1 = WT + (size_t)(n0 + r1) * K + c1 * 8;
  u16* lA0 = &sA[(wave * 128 + lane) * 8];
  u16* lA1 = &sA[(wave * 128 + 64 + lane) * 8];
  u16* lB0 = &sB[(wave * 128 + lane) * 8];
  u16* lB1 = &sB[(wave * 128 + 64 + lane) * 8];

  f32x4 acc[4][4];
  #pragma unroll
  for (int i = 0; i < 4; ++i)
    #pragma unroll
    for (int j = 0; j < 4; ++j) acc[i][j] = (f32x4){0.f, 0.f, 0.f, 0.f};

  for (int k0 = 0; k0 < K; k0 += 32) {
    __syncthreads();  // prior frag reads done before overwrite
    gload16(gA0 + k0, lA0);
    gload16(gA1 + k0, lA1);
    gload16(gB0 + k0, lB0);
    gload16(gB1 + k0, lB1);
    __syncthreads();  // compiler drains vmcnt(0) before barrier
    short8 af[4], bf[4];
    #pragma unroll
    for (int i = 0; i < 4; ++i) {
      int ra = wm + i * 16 + l15;
      af[i] = *(const short8*)&sA[ra * 32 + (quad ^ ((ra >> 1) & 3)) * 8];
    }
    #pragma unroll
    for (int j = 0; j < 4; ++j) {
      int rb = wn + j * 16 + l15;
      bf[j] = *(const short8*)&sB[rb * 32 + (quad ^ ((rb >> 1) & 3)) * 8];
    }
    #pragma unroll
    for (int i = 0; i < 4; ++i)
      #pragma unroll
      for (int j = 0; j < 4; ++j)
        acc[i][j] = __builtin_amdgcn_mfma_f32_16x16x32_bf16(af[i], bf[j], acc[i][j], 0, 0, 0);
  }

  // epilogue: D row = quad*4+reg (m), col = lane&15 (n)  [m89-verified]
  #pragma unroll
  for (int i = 0; i < 4; ++i) {
    int mBase = m0 + wm + i * 16 + quad * 4;
    #pragma unroll
    for (int r = 0; r < 4; ++r) {
      int m = mBase + r;
      if (m < M) {
        #pragma unroll
        for (int j = 0; j < 4; ++j) {
          int n = n0 + wn + j * 16 + l15;
          float v = acc[i][j][r] + bias[n];
          if (RESID) v += R[(size_t)m * N + n];
          if (RELU) v = fmaxf(v, 0.f);
          if constexpr (sizeof(TC) == 2) ((u16*)C)[(size_t)m * N + n] = f2b(v);
          else ((float*)C)[(size_t)m * N + n] = v;
        }
      }
    }
  }
}

// ---------- in-place LayerNorm, also emits bf16 shadow ----------
__global__ __launch_bounds__(256) void ln_k(float* h, u16* __restrict__ hb,
    const float* __restrict__ g, const float* __restrict__ bb)
{
  __shared__ float rs[256], rq[256];
  float* p = h + (size_t)blockIdx.x * 512;
  u16* pb = hb + (size_t)blockIdx.x * 512;
  int t = threadIdx.x;
  float v0 = p[t], v1 = p[t + 256];
  rs[t] = v0 + v1; rq[t] = v0 * v0 + v1 * v1;
  __syncthreads();
  for (int o = 128; o > 0; o >>= 1) {
    if (t < o) { rs[t] += rs[t + o]; rq[t] += rq[t + o]; }
    __syncthreads();
  }
  float mean = rs[0] * (1.f / 512.f);
  float var = fmaxf(rq[0] * (1.f / 512.f) - mean * mean, 0.f);
  float rinv = rsqrtf(var + 1e-5f);
  float o0 = (v0 - mean) * rinv * g[t] + bb[t];
  float o1 = (v1 - mean) * rinv * g[t + 256] + bb[t + 256];
  p[t] = o0; p[t + 256] = o1;
  pb[t] = f2b(o0); pb[t + 256] = f2b(o1);
}

// ---------- sparse block attention (bf16 qkv in, bf16 av out) — validated r7 version ----------
__global__ __launch_bounds__(128) void attnb_k(const u16* __restrict__ qkv, u16* __restrict__ av,
    const int* __restrict__ rnd, int S, int Sp, int nb)
{
  __shared__ float sS[8][80];
  __shared__ float sQ[8][64];
  __shared__ int sJB[10], sVD[10];
  int t = threadIdx.x;
  int n = blockIdx.x % nb;
  int r1 = blockIdx.x / nb;
  int hh = r1 & 7, b = r1 >> 3;
  const u16* base = qkv + (size_t)b * Sp * 1536;

  if (t < 10) {
    int jb, vd;
    if (t < 2) { jb = t; vd = 1; }
    else if (t < 7) {
      int w = n + t - 4;
      vd = (w >= 0 && w < nb) ? 1 : 0;
      jb = w < 0 ? 0 : (w > nb - 1 ? nb - 1 : w);
    } else { jb = rnd[n * 3 + t - 7]; vd = 1; }
    sJB[t] = jb; sVD[t] = vd;
  }
  {
    int idx4 = t * 4;
    int qi = idx4 >> 6, c = idx4 & 63;
    ushort4 u = *(const ushort4*)(base + (size_t)(n * 8 + qi) * 1536 + hh * 64 + c);
    sQ[qi][c] = b2f(u.x); sQ[qi][c + 1] = b2f(u.y); sQ[qi][c + 2] = b2f(u.z); sQ[qi][c + 3] = b2f(u.w);
  }
  __syncthreads();
  if (t < 80) {
    int kb = t >> 3, kj = t & 7;
    int tok = sJB[kb] * 8 + kj;
    const u16* kp = base + (size_t)tok * 1536 + 512 + hh * 64;
    bool ok = sVD[kb] && (tok < S);
    float d8[8];
    #pragma unroll
    for (int qi = 0; qi < 8; ++qi) d8[qi] = 0.f;
    for (int c = 0; c < 64; c += 4) {
      ushort4 u = *(const ushort4*)(kp + c);
      float k0 = b2f(u.x), k1 = b2f(u.y), k2 = b2f(u.z), k3 = b2f(u.w);
      #pragma unroll
      for (int qi = 0; qi < 8; ++qi)
        d8[qi] += sQ[qi][c] * k0 + sQ[qi][c + 1] * k1 + sQ[qi][c + 2] * k2 + sQ[qi][c + 3] * k3;
    }
    #pragma unroll
    for (int qi = 0; qi < 8; ++qi) sS[qi][t] = ok ? d8[qi] * 0.125f : -1.0e9f;
  }
  __syncthreads();
  if (t < 8) {
    float mx = -3.0e38f;
    for (int k = 0; k < 80; ++k) mx = fmaxf(mx, sS[t][k]);
    float sum = 0.f;
    for (int k = 0; k < 80; ++k) { float e = __expf(sS[t][k] - mx); sS[t][k] = e; sum += e; }
    float inv = 1.f / sum;
    for (int k = 0; k < 80; ++k) sS[t][k] *= inv;
  }
  __syncthreads();
  {
    int qi = t >> 4, dd = (t & 15) << 2;
    float o0 = 0, o1 = 0, o2 = 0, o3 = 0;
    for (int k = 0; k < 80; ++k) {
      float pp = sS[qi][k];
      int tok = sJB[k >> 3] * 8 + (k & 7);
      ushort4 u = *(const ushort4*)(base + (size_t)tok * 1536 + 1024 + hh * 64 + dd);
      o0 += pp * b2f(u.x); o1 += pp * b2f(u.y); o2 += pp * b2f(u.z); o3 += pp * b2f(u.w);
    }
    ushort4 u; u.x = f2b(o0); u.y = f2b(o1); u.z = f2b(o2); u.w = f2b(o3);
    *(ushort4*)(av + ((size_t)b * Sp + n * 8 + qi) * 512 + hh * 64 + dd) = u;
  }
}

// ---------- VAE head ----------
__global__ __launch_bounds__(512) void head_k(const float* __restrict__ h,
    const float* __restrict__ Wm, const float* __restrict__ bm,
    const float* __restrict__ Wlv, const float* __restrict__ blv,
    const float* __restrict__ eps, float* __restrict__ z, float* out_elbo)
{
  __shared__ float red[512];
  int t = threadIdx.x;
  int b = t >> 4, i = t & 15;
  const float* p = h + (size_t)b * SPENC * 512;
  float am = bm[i], al = blv[i];
  for (int c = 0; c < 512; ++c) {
    float pv = p[c];
    am += pv * Wm[c * 16 + i];
    al += pv * Wlv[c * 16 + i];
  }
  z[t] = am + eps[t] * expf(0.5f * al);
  red[t] = -0.5f * (1.f + al - am * am - expf(al));
  __syncthreads();
  for (int o = 256; o > 0; o >>= 1) { if (t < o) red[t] += red[t + o]; __syncthreads(); }
  if (t == 0) out_elbo[0] = red[0] * (1.f / 32.f);
}

// ---------- seq ----------
__global__ __launch_bounds__(256) void seq_k(const float* __restrict__ z, const float* __restrict__ We,
    const float* __restrict__ be, float* __restrict__ seq)
{
  int gid = blockIdx.x * 256 + threadIdx.x;
  int b = gid >> 11, c = gid & 2047;
  float acc = be[c];
  #pragma unroll
  for (int i = 0; i < 16; ++i) acc += z[b * 16 + i] * We[i * 2048 + c];
  seq[gid] = acc;
}

// ---------- decoder init: h fp32 + hb bf16 ----------
__global__ __launch_bounds__(256) void decinit_k(const float* __restrict__ seq, const float* __restrict__ Wc,
    const float* __restrict__ bc, const float* __restrict__ emb, float* __restrict__ h, u16* __restrict__ hb)
{
  size_t gid = (size_t)blockIdx.x * 256 + threadIdx.x;
  int dd = (int)(gid & 511);
  size_t rs = gid >> 9;
  int s = (int)(rs & 1023);
  int b = (int)(rs >> 10);
  float v = seq[b * 2048 + s] * Wc[dd] + seq[b * 2048 + 1024 + s] * Wc[512 + dd]
          + bc[dd] + emb[(size_t)s * 512 + dd];
  h[gid] = v;
  hb[gid] = f2b(v);
}

// ---------- final ----------
__global__ __launch_bounds__(256) void final_k(const float* __restrict__ h, const float* __restrict__ Ws,
    const float* __restrict__ bs, float* __restrict__ out)
{
  int gid = blockIdx.x * 256 + threadIdx.x;
  int nn = gid & 15;
  int rs = gid >> 4;
  const float* p = h + (size_t)rs * 512;
  float acc = bs[nn];
  for (int c = 0; c < 512; ++c) acc += p[c] * Ws[c * 16 + nn];
  out[gid] = acc;
}

extern "C" void kernel_launch(void* const* d_in, const int* in_sizes, int n_in,
                              void* d_out, int out_size, void* d_ws, size_t ws_size,
                              hipStream_t stream) {
  float* out = (float*)d_out;
  (void)out_size; (void)ws_size;

  static const int EXP_DICT[30] = {
    524288, 512, 524800, 524288, 8192, 512, 7864320, 15360, 2621440, 5120,
    5120, 5120, 10485760, 20480, 10485760, 5120, 5120, 5120, 8192, 16,
    8192, 16, 32768, 2048, 1024, 512, 8192, 16, 387, 384 };
  bool dict_ok = (n_in == 30);
  if (dict_ok) for (int i = 0; i < 30; ++i) if (in_sizes[i] != EXP_DICT[i]) { dict_ok = false; break; }
  if (!dict_ok) { beacon_k<<<1, 64, 0, stream>>>(out); return; }

  const float* x      = (const float*)d_in[0];
  const float* eps    = (const float*)d_in[1];
  const float* emb_in = (const float*)d_in[2];
  const float* emb_out= (const float*)d_in[3];
  const float* W_data = (const float*)d_in[4];
  const float* b_data = (const float*)d_in[5];
  const float* Wqkv   = (const float*)d_in[6];
  const float* bqkv   = (const float*)d_in[7];
  const float* Wo     = (const float*)d_in[8];
  const float* bo     = (const float*)d_in[9];
  const float* ln1g   = (const float*)d_in[10];
  const float* ln1b   = (const float*)d_in[11];
  const float* W1     = (const float*)d_in[12];
  const float* b1     = (const float*)d_in[13];
  const float* W2     = (const float*)d_in[14];
  const float* b2     = (const float*)d_in[15];
  const float* ln2g   = (const float*)d_in[16];
  const float* ln2b   = (const float*)d_in[17];
  const float* Wm     = (const float*)d_in[18];
  const float* bm     = (const float*)d_in[19];
  const float* Wlv    = (const float*)d_in[20];
  const float* blv    = (const float*)d_in[21];
  const float* Wexp   = (const float*)d_in[22];
  const float* bexp   = (const float*)d_in[23];
  const float* Wconv  = (const float*)d_in[24];
  const float* bconv  = (const float*)d_in[25];
  const float* Wseq   = (const float*)d_in[26];
  const float* bseq   = (const float*)d_in[27];
  const int* rand_enc = (const int*)d_in[28];
  const int* rand_dec = (const int*)d_in[29];

  // ---- workspace carve (~198.4 MB; proven-safe envelope 203 MB) ----
  char* ws = (char*)d_ws;
  float* h     = (float*)ws;                         // 67,633,152
  u16*   hb    = (u16*)(ws + 67633152);              // 33,816,576
  u16*   WTqkv = (u16*)(ws + 101449728);             // 15,728,640
  u16*   WTo   = (u16*)(ws + 117178368);             //  5,242,880
  u16*   WT1   = (u16*)(ws + 122421248);             // 20,971,520
  u16*   WT2   = (u16*)(ws + 143392768);             // 20,971,520
  u16*   qkvb  = (u16*)(ws + 164364288);             // 25,362,432 (8*1032*1536 bf16)
  u16*   avb   = (u16*)(ws + 189726720);             //  8,454,144 (8*1032*512 bf16)
  u16*   ffnb  = (u16*)(ws + 164364288);             // 33,554,432 (union; 8192*2048 bf16)
  float* seqb  = (float*)(ws + 198180864);           //    262,144
  float* z     = (float*)(ws + 198443008);           //      2,048

  // ---- weight transpose+convert ----
  tr_k<<<dim3(512 / 32, 1536 / 32, 10), 256, 0, stream>>>(Wqkv, WTqkv, 512, 1536);
  tr_k<<<dim3(512 / 32, 512 / 32, 10), 256, 0, stream>>>(Wo, WTo, 512, 512);
  tr_k<<<dim3(512 / 32, 2048 / 32, 10), 256, 0, stream>>>(W1, WT1, 512, 2048);
  tr_k<<<dim3(2048 / 32, 512 / 32, 10), 256, 0, stream>>>(W2, WT2, 2048, 512);

  // ===== encoder: M=33024; attention path in 4 chunks of 8 batches (Mc=8256) =====
  {
    const int M = MENC;
    embed_k<<<(M * 512) / 256, 256, 0, stream>>>(x, W_data, b_data, emb_in, h, hb);
    for (int i = 0; i < 5; ++i) {
      for (int bc = 0; bc < 4; ++bc) {
        size_t roff = (size_t)bc * 8 * SPENC * 512;
        const int Mc = 8 * SPENC;  // 8256
        const int ty = 65;         // ceil(8256/128)
        mgemm_k<u16, false, false><<<dim3(1536 / 128, ty), 256, 0, stream>>>(
            hb + roff, WTqkv + (size_t)i * 512 * 1536, bqkv + (size_t)i * 1536, nullptr, qkvb, Mc, 1536, 512, 512);
        attnb_k<<<8 * 8 * NBE, 128, 0, stream>>>(qkvb, avb, rand_enc, SENC, SPENC, NBE);
        mgemm_k<float, false, true><<<dim3(512 / 128, ty), 256, 0, stream>>>(
            avb, WTo + (size_t)i * 512 * 512, bo + (size_t)i * 512, h + roff, h + roff, Mc, 512, 512, 512);
      }
      ln_k<<<M, 256, 0, stream>>>(h, hb, ln1g + (size_t)i * 512, ln1b + (size_t)i * 512);
      for (int off = 0; off < M; off += 8192) {
        int Mc = (M - off < 8192) ? (M - off) : 8192;
        int ty = (Mc + 127) / 128;
        mgemm_k<u16, true, false><<<dim3(2048 / 128, ty), 256, 0, stream>>>(
            hb + (size_t)off * 512, WT1 + (size_t)i * 512 * 2048, b1 + (size_t)i * 2048, nullptr, ffnb, Mc, 2048, 512, 512);
        mgemm_k<float, false, true><<<dim3(512 / 128, ty), 256, 0, stream>>>(
            ffnb, WT2 + (size_t)i * 2048 * 512, b2 + (size_t)i * 512, h + (size_t)off * 512, h + (size_t)off * 512, Mc, 512, 2048, 2048);
      }
      ln_k<<<M, 256, 0, stream>>>(h, hb, ln2g + (size_t)i * 512, ln2b + (size_t)i * 512);
    }
  }

  // ===== VAE head =====
  head_k<<<1, 512, 0, stream>>>(h, Wm, bm, Wlv, blv, eps, z, out + 524288);
  seq_k<<<256, 256, 0, stream>>>(z, Wexp, bexp, seqb);
  decinit_k<<<(MDEC * 512) / 256, 256, 0, stream>>>(seqb, Wconv, bconv, emb_out, h, hb);

  // ===== decoder: M=32768; attention path in 4 chunks of 8 batches (Mc=8192) =====
  {
    const int M = MDEC;
    for (int i = 5; i < 10; ++i) {
      for (int bc = 0; bc < 4; ++bc) {
        size_t roff = (size_t)bc * 8 * SDEC * 512;
        const int Mc = 8 * SDEC;  // 8192
        const int ty = 64;
        mgemm_k<u16, false, false><<<dim3(1536 / 128, ty), 256, 0, stream>>>(
            hb + roff, WTqkv + (size_t)i * 512 * 1536, bqkv + (size_t)i * 1536, nullptr, qkvb, Mc, 1536, 512, 512);
        attnb_k<<<8 * 8 * NBD, 128, 0, stream>>>(qkvb, avb, rand_dec, SDEC, SDEC, NBD);
        mgemm_k<float, false, true><<<dim3(512 / 128, ty), 256, 0, stream>>>(
            avb, WTo + (size_t)i * 512 * 512, bo + (size_t)i * 512, h + roff, h + roff, Mc, 512, 512, 512);
      }
      ln_k<<<M, 256, 0, stream>>>(h, hb, ln1g + (size_t)i * 512, ln1b + (size_t)i * 512);
      for (int off = 0; off < M; off += 8192) {
        const int Mc = 8192;
        mgemm_k<u16, true, false><<<dim3(2048 / 128, 64), 256, 0, stream>>>(
            hb + (size_t)off * 512, WT1 + (size_t)i * 512 * 2048, b1 + (size_t)i * 2048, nullptr, ffnb, Mc, 2048, 512, 512);
        mgemm_k<float, false, true><<<dim3(512 / 128, 64), 256, 0, stream>>>(
            ffnb, WT2 + (size_t)i * 2048 * 512, b2 + (size_t)i * 512, h + (size_t)off * 512, h + (size_t)off * 512, Mc, 512, 2048, 2048);
      }
      ln_k<<<M, 256, 0, stream>>>(h, hb, ln2g + (size_t)i * 512, ln2b + (size_t)i * 512);
    }
  }

  // ===== output =====
  final_k<<<524288 / 256, 256, 0, stream>>>(h, Wseq, bseq, out);
}